// Round 5
// baseline (1076.804 us; speedup 1.0000x reference)
//
#include <hip/hip_runtime.h>
#include <math.h>
#include <stdint.h>

// MultiHeadAttention: B=2,S=2048,D=768,H=12,depth=64
// out = (softmax(mask(QK^T/8)) V) Wo^T + bo ; also returns attn itself.
// d_out = [out (B*S*D) | attn (B*H*S*S)] fp32.
//
// Pipeline (round 2 design, resubmitted after three broker timeouts):
// projections (split-bf16 MFMA) ->
//   scores_strip: raw masked/scaled scores + online per-row (max, sum) stats ->
//   pv_fused: normalize in place (writes attn) + PV MFMA -> output projection.
// Softmax as a standalone 804MB-traffic kernel is gone.
constexpr int B_ = 2, S_ = 2048, D_ = 768, H_ = 12, DP_ = 64;
constexpr int M_ = B_ * S_;                              // 4096 rows
constexpr size_t HS_ELEMS = (size_t)B_ * H_ * S_ * DP_;  // head-split tensor elems
constexpr size_t OUT_ELEMS = (size_t)M_ * D_;
constexpr size_t NROWS = (size_t)B_ * H_ * S_;           // attn row count

typedef __bf16 bf16_t;
typedef bf16_t bf16x8 __attribute__((ext_vector_type(8)));
typedef float f32x4 __attribute__((ext_vector_type(4)));

__device__ __forceinline__ f32x4 mfma16(bf16x8 a, bf16x8 b, f32x4 c) {
  return __builtin_amdgcn_mfma_f32_16x16x32_bf16(a, b, c, 0, 0, 0);
}

__device__ __forceinline__ float truncbf(float x) {
  return __uint_as_float(__float_as_uint(x) & 0xFFFF0000u);
}
__device__ __forceinline__ uint32_t pack_hi2(float x, float y) {
  return (__float_as_uint(x) >> 16) | (__float_as_uint(y) & 0xFFFF0000u);
}
__device__ __forceinline__ uint32_t pack_lo2(float x, float y) {
  const float lx = x - truncbf(x);   // exact (Sterbenz)
  const float ly = y - truncbf(y);
  return (__float_as_uint(lx) >> 16) | (__float_as_uint(ly) & 0xFFFF0000u);
}
// 8 consecutive floats -> hi/lo planes, packed 2 bf16 per uint.
__device__ __forceinline__ void cvt8(const float4 a, const float4 b, uint4& H, uint4& L) {
  H.x = pack_hi2(a.x, a.y); H.y = pack_hi2(a.z, a.w);
  H.z = pack_hi2(b.x, b.y); H.w = pack_hi2(b.z, b.w);
  L.x = pack_lo2(a.x, a.y); L.y = pack_lo2(a.z, a.w);
  L.z = pack_lo2(b.x, b.y); L.w = pack_lo2(b.z, b.w);
}

// LDS tiles are [rows][64] bf16 (128B rows = 8 slots of 16B). Slot index is
// XOR-swizzled by (row&7): conflict-free ds_read_b128 fragment loads (T2/G4).
__device__ __forceinline__ bf16x8 ldfrag(const uint16_t (*T)[64], int row, int slot) {
  return *(const bf16x8*)&T[row][(slot ^ (row & 7)) << 3];
}

// ---------------------------------------------------------------------------
// Projections  Y = X @ W^T + bias.  X:[M,768], W:[768,768], both K-contiguous.
// 128x128 tile, BK=64, 256 threads = 4 waves (2x2 of 64x64), split-bf16 MFMA.
// MODE: 0 flat [M,768]; 1 headsplit [B,H,S,64]; 2 headsplit-transposed [B,H,64,S]
// ---------------------------------------------------------------------------
template <int MODE>
__global__ __launch_bounds__(256) void xwt_mfma(const float* __restrict__ X,
                                                const float* __restrict__ W,
                                                const float* __restrict__ bias,
                                                float* __restrict__ Y) {
  __shared__ alignas(16) uint16_t Xh[128][64], Xl[128][64], Wh[128][64], Wl[128][64];
  const float* Xb = X + (size_t)blockIdx.x * 128 * D_;
  const float* Wb = W + (size_t)blockIdx.y * 128 * D_;
  const int t = threadIdx.x;
  const int lane = t & 63, wid = t >> 6;
  const int wm = (wid >> 1) * 64, wn = (wid & 1) * 64;
  const int r = lane & 15, g = lane >> 4;
  f32x4 acc[4][4] = {};
  for (int k0 = 0; k0 < D_; k0 += 64) {
    __syncthreads();  // protect previous iteration's fragment reads
#pragma unroll
    for (int i = 0; i < 8; ++i) {
      const int u = t + i * 256;
      const int tens = u >> 10;  // 0 = X, 1 = W (uniform per unrolled i)
      const int idx = u & 1023;
      const int row = idx >> 3, sl = idx & 7;
      const float* src = (tens ? Wb : Xb) + (size_t)row * D_ + k0 + sl * 8;
      const float4 a = *(const float4*)src;
      const float4 b = *(const float4*)(src + 4);
      uint4 H, L; cvt8(a, b, H, L);
      const int ps = (sl ^ (row & 7)) << 3;
      if (tens) { *(uint4*)&Wh[row][ps] = H; *(uint4*)&Wl[row][ps] = L; }
      else      { *(uint4*)&Xh[row][ps] = H; *(uint4*)&Xl[row][ps] = L; }
    }
    __syncthreads();
#pragma unroll
    for (int ks = 0; ks < 2; ++ks) {
      const int slot = ks * 4 + g;
      bf16x8 aH[4], aL[4], bH[4], bL[4];
#pragma unroll
      for (int mi = 0; mi < 4; ++mi) {
        const int row = wm + mi * 16 + r;
        aH[mi] = ldfrag(Xh, row, slot); aL[mi] = ldfrag(Xl, row, slot);
      }
#pragma unroll
      for (int ni = 0; ni < 4; ++ni) {
        const int row = wn + ni * 16 + r;
        bH[ni] = ldfrag(Wh, row, slot); bL[ni] = ldfrag(Wl, row, slot);
      }
#pragma unroll
      for (int mi = 0; mi < 4; ++mi)
#pragma unroll
        for (int ni = 0; ni < 4; ++ni) {
          acc[mi][ni] = mfma16(aH[mi], bH[ni], acc[mi][ni]);
          acc[mi][ni] = mfma16(aH[mi], bL[ni], acc[mi][ni]);
          acc[mi][ni] = mfma16(aL[mi], bH[ni], acc[mi][ni]);
        }
    }
  }
  const int m0 = blockIdx.x * 128 + wm;
  const int n0 = blockIdx.y * 128 + wn;
#pragma unroll
  for (int mi = 0; mi < 4; ++mi) {
    const int rowb = m0 + mi * 16 + 4 * g;  // + j
#pragma unroll
    for (int ni = 0; ni < 4; ++ni) {
      const int col = n0 + ni * 16 + r;
      const float bv = bias[col];
      if (MODE == 0) {
        float* dst = Y + (size_t)rowb * D_ + col;
#pragma unroll
        for (int j = 0; j < 4; ++j) dst[(size_t)j * D_] = acc[mi][ni][j] + bv;
      } else if (MODE == 1) {
        const int h = col >> 6, d = col & 63;
#pragma unroll
        for (int j = 0; j < 4; ++j) {
          const int m = rowb + j;
          const int b = m >> 11, s = m & (S_ - 1);
          Y[(((size_t)b * H_ + h) * S_ + s) * DP_ + d] = acc[mi][ni][j] + bv;
        }
      } else {  // MODE 2: Vt[b][h][d][s] — 4 consecutive s => float4
        const int h = col >> 6, d = col & 63;
        const int b = rowb >> 11, s = rowb & (S_ - 1);
        float4 o;
        o.x = acc[mi][ni][0] + bv; o.y = acc[mi][ni][1] + bv;
        o.z = acc[mi][ni][2] + bv; o.w = acc[mi][ni][3] + bv;
        *(float4*)(Y + (((size_t)b * H_ + h) * DP_ + d) * S_ + s) = o;
      }
    }
  }
}

// ---------------------------------------------------------------------------
// scores_strip: per (b,h), one block owns 128 q-rows x all 2048 keys.
// Writes raw masked/scaled scores to P (attn buffer) AND per-row online
// softmax stats: mstat[bh*S+q] = rowmax, mstat[NROWS + bh*S+q] = 1/sum.
// Masked scores are written as -1e30f (exp underflows to exactly 0 later).
// ---------------------------------------------------------------------------
__global__ __launch_bounds__(256) void scores_strip(const float* __restrict__ Q,
                                                    const float* __restrict__ K,
                                                    const int* __restrict__ mask,
                                                    float* __restrict__ P,
                                                    float* __restrict__ mstat) {
  __shared__ alignas(16) uint16_t Qh[128][64], Ql[128][64], Kh[128][64], Kl[128][64];
  __shared__ float mred[2][2][64], sred[2][2][64];
  const int bh = blockIdx.y;
  const int qbase = blockIdx.x * 128;
  const float* Qb = Q + ((size_t)bh * S_ + qbase) * DP_;
  const float* Kb = K + (size_t)bh * S_ * DP_;
  float* Pb = P + ((size_t)bh * S_ + qbase) * S_;
  const int* mb = mask + (size_t)(bh / H_) * S_;
  const int t = threadIdx.x;
  // stage Q (128x64) once
#pragma unroll
  for (int i = 0; i < 4; ++i) {
    const int u = t + i * 256;
    const int row = u >> 3, sl = u & 7;
    const float* src = Qb + (size_t)row * DP_ + sl * 8;
    const float4 a = *(const float4*)src;
    const float4 b = *(const float4*)(src + 4);
    uint4 H, L; cvt8(a, b, H, L);
    const int ps = (sl ^ (row & 7)) << 3;
    *(uint4*)&Qh[row][ps] = H; *(uint4*)&Ql[row][ps] = L;
  }
  const int lane = t & 63, wid = t >> 6;
  const int wm = (wid >> 1) * 64, wn = (wid & 1) * 64;
  const int r = lane & 15, g = lane >> 4;
  float m_[4][4], s_[4][4];
#pragma unroll
  for (int a = 0; a < 4; ++a)
#pragma unroll
    for (int b = 0; b < 4; ++b) { m_[a][b] = -3e38f; s_[a][b] = 0.f; }

  for (int kt = 0; kt < 16; ++kt) {
    __syncthreads();  // protect previous iteration's K-tile reads
#pragma unroll
    for (int i = 0; i < 4; ++i) {
      const int u = t + i * 256;
      const int row = u >> 3, sl = u & 7;
      const float* src = Kb + (size_t)(kt * 128 + row) * DP_ + sl * 8;
      const float4 a = *(const float4*)src;
      const float4 b = *(const float4*)(src + 4);
      uint4 H, L; cvt8(a, b, H, L);
      const int ps = (sl ^ (row & 7)) << 3;
      *(uint4*)&Kh[row][ps] = H; *(uint4*)&Kl[row][ps] = L;
    }
    __syncthreads();
    f32x4 acc[4][4] = {};
#pragma unroll
    for (int ks = 0; ks < 2; ++ks) {
      const int slot = ks * 4 + g;
      bf16x8 aH[4], aL[4], bH[4], bL[4];
#pragma unroll
      for (int mi = 0; mi < 4; ++mi) {
        const int row = wm + mi * 16 + r;
        aH[mi] = ldfrag(Qh, row, slot); aL[mi] = ldfrag(Ql, row, slot);
      }
#pragma unroll
      for (int ni = 0; ni < 4; ++ni) {
        const int row = wn + ni * 16 + r;
        bH[ni] = ldfrag(Kh, row, slot); bL[ni] = ldfrag(Kl, row, slot);
      }
#pragma unroll
      for (int mi = 0; mi < 4; ++mi)
#pragma unroll
        for (int ni = 0; ni < 4; ++ni) {
          acc[mi][ni] = mfma16(aH[mi], bH[ni], acc[mi][ni]);
          acc[mi][ni] = mfma16(aH[mi], bL[ni], acc[mi][ni]);
          acc[mi][ni] = mfma16(aL[mi], bH[ni], acc[mi][ni]);
        }
    }
    // mask + scale + write raw scores + online (max,sum) update
    int msk[4];
#pragma unroll
    for (int ni = 0; ni < 4; ++ni) msk[ni] = mb[kt * 128 + wn + ni * 16 + r];
#pragma unroll
    for (int mi = 0; mi < 4; ++mi) {
      float tv[4][4];
#pragma unroll
      for (int ni = 0; ni < 4; ++ni)
#pragma unroll
        for (int j = 0; j < 4; ++j) {
          const float sv = msk[ni] ? acc[mi][ni][j] * 0.125f : -1e30f;
          tv[ni][j] = sv;
          Pb[(size_t)(wm + mi * 16 + 4 * g + j) * S_ + kt * 128 + wn + ni * 16 + r] = sv;
        }
#pragma unroll
      for (int j = 0; j < 4; ++j) {
        const float rm = fmaxf(fmaxf(tv[0][j], tv[1][j]), fmaxf(tv[2][j], tv[3][j]));
        const float mn = fmaxf(m_[mi][j], rm);
        float ssum = s_[mi][j] * __expf(m_[mi][j] - mn);
#pragma unroll
        for (int ni = 0; ni < 4; ++ni)
          ssum += (tv[ni][j] <= -1e29f) ? 0.f : __expf(tv[ni][j] - mn);
        s_[mi][j] = ssum; m_[mi][j] = mn;
      }
    }
  }
  // combine partial (m,s) across the 16 r-lanes (they saw different keys)
#pragma unroll
  for (int off = 1; off < 16; off <<= 1) {
#pragma unroll
    for (int mi = 0; mi < 4; ++mi)
#pragma unroll
      for (int j = 0; j < 4; ++j) {
        const float om = __shfl_xor(m_[mi][j], off);
        const float os = __shfl_xor(s_[mi][j], off);
        const float mn = fmaxf(m_[mi][j], om);
        s_[mi][j] = s_[mi][j] * __expf(m_[mi][j] - mn) + os * __expf(om - mn);
        m_[mi][j] = mn;
      }
  }
  // combine across the two wn-half waves via LDS, then write stats
  if (r == 0) {
#pragma unroll
    for (int mi = 0; mi < 4; ++mi)
#pragma unroll
      for (int j = 0; j < 4; ++j) {
        mred[wid >> 1][wid & 1][mi * 16 + 4 * g + j] = m_[mi][j];
        sred[wid >> 1][wid & 1][mi * 16 + 4 * g + j] = s_[mi][j];
      }
  }
  __syncthreads();
  if (t < 128) {
    const int half = t >> 6, rowid = t & 63;
    const float m0 = mred[half][0][rowid], m1 = mred[half][1][rowid];
    const float s0 = sred[half][0][rowid], s1 = sred[half][1][rowid];
    const float mn = fmaxf(m0, m1);
    const float s = s0 * __expf(m0 - mn) + s1 * __expf(m1 - mn);
    const size_t q = (size_t)bh * S_ + qbase + half * 64 + rowid;
    mstat[q] = mn;
    mstat[NROWS + q] = 1.0f / s;
  }
}

// ---------------------------------------------------------------------------
// pv_fused: per (b,h), block owns 128 q-rows. Reads raw scores, computes
// p = exp(s - m) * inv, writes normalized attn IN PLACE, converts p to
// split-bf16 A-fragments in-register and accumulates O = P @ V against
// LDS-staged swizzled Vt tiles. Writes ctx in concat layout [B,S,768].
// A/B fragment key-mapping is identical on both operands (perm-invariant).
// ---------------------------------------------------------------------------
__global__ __launch_bounds__(256) void pv_fused(float* __restrict__ P,
                                                const float* __restrict__ Vt,
                                                const float* __restrict__ mstat,
                                                float* __restrict__ C) {
  __shared__ alignas(16) uint16_t Vh[64][64], Vl[64][64];
  __shared__ float mrow[128], irow[128];
  const int bh = blockIdx.y;
  const int b = bh / H_, h = bh % H_;
  const int qbase = blockIdx.x * 128;
  float* Pb = P + ((size_t)bh * S_ + qbase) * S_;
  const float* Vb = Vt + (size_t)bh * DP_ * S_;
  const int t = threadIdx.x;
  if (t < 128) {
    const size_t q = (size_t)bh * S_ + qbase + t;
    mrow[t] = mstat[q];
    irow[t] = mstat[NROWS + q];
  }
  const int lane = t & 63, w = t >> 6;
  const int r = lane & 15, g = lane >> 4;
  f32x4 acc[2][4] = {};
  for (int kt = 0; kt < 32; ++kt) {
    __syncthreads();  // protect previous V-tile reads (and mrow/irow writes)
#pragma unroll
    for (int i = 0; i < 2; ++i) {
      const int u = t + i * 256;        // 512 chunks of 8 floats = 64x64
      const int row = u >> 3, sl = u & 7;
      const float* src = Vb + (size_t)row * S_ + kt * 64 + sl * 8;
      const float4 a = *(const float4*)src;
      const float4 bq = *(const float4*)(src + 4);
      uint4 H, L; cvt8(a, bq, H, L);
      const int ps = (sl ^ (row & 7)) << 3;
      *(uint4*)&Vh[row][ps] = H; *(uint4*)&Vl[row][ps] = L;
    }
    __syncthreads();
#pragma unroll
    for (int ks = 0; ks < 2; ++ks) {
      bf16x8 aH[2], aL[2];
#pragma unroll
      for (int mi = 0; mi < 2; ++mi) {
        const int qloc = w * 32 + mi * 16 + r;
        float* src = Pb + (size_t)qloc * S_ + kt * 64 + ks * 32 + g * 8;
        float4 p0 = *(const float4*)src;
        float4 p1 = *(const float4*)(src + 4);
        const float mq = mrow[qloc], iv = irow[qloc];
        p0.x = __expf(p0.x - mq) * iv; p0.y = __expf(p0.y - mq) * iv;
        p0.z = __expf(p0.z - mq) * iv; p0.w = __expf(p0.w - mq) * iv;
        p1.x = __expf(p1.x - mq) * iv; p1.y = __expf(p1.y - mq) * iv;
        p1.z = __expf(p1.z - mq) * iv; p1.w = __expf(p1.w - mq) * iv;
        *(float4*)src = p0;             // attn output, in place
        *(float4*)(src + 4) = p1;
        uint4 H, L; cvt8(p0, p1, H, L);
        aH[mi] = *(bf16x8*)&H; aL[mi] = *(bf16x8*)&L;
      }
      const int k16 = ks * 4 + g;
#pragma unroll
      for (int ni = 0; ni < 4; ++ni) {
        const int drow = ni * 16 + r;
        const bf16x8 bH = *(const bf16x8*)&Vh[drow][(k16 ^ (drow & 7)) << 3];
        const bf16x8 bL = *(const bf16x8*)&Vl[drow][(k16 ^ (drow & 7)) << 3];
#pragma unroll
        for (int mi = 0; mi < 2; ++mi) {
          acc[mi][ni] = mfma16(aH[mi], bH, acc[mi][ni]);
          acc[mi][ni] = mfma16(aH[mi], bL, acc[mi][ni]);
          acc[mi][ni] = mfma16(aL[mi], bH, acc[mi][ni]);
        }
      }
    }
  }
  // epilogue: ctx concat layout C[b][q][h*64+d]
#pragma unroll
  for (int mi = 0; mi < 2; ++mi) {
    const int q0 = qbase + w * 32 + mi * 16 + 4 * g;
#pragma unroll
    for (int ni = 0; ni < 4; ++ni) {
      const int d = ni * 16 + r;
#pragma unroll
      for (int j = 0; j < 4; ++j)
        C[(size_t)(b * S_ + q0 + j) * D_ + h * DP_ + d] = acc[mi][ni][j];
    }
  }
}

extern "C" void kernel_launch(void* const* d_in, const int* in_sizes, int n_in,
                              void* d_out, int out_size, void* d_ws, size_t ws_size,
                              hipStream_t stream) {
  (void)in_sizes; (void)n_in; (void)out_size; (void)ws_size;
  const float* q = (const float*)d_in[0];
  const float* k = (const float*)d_in[1];
  const float* v = (const float*)d_in[2];
  const int* mask = (const int*)d_in[3];
  const float* wq_w = (const float*)d_in[4];
  const float* wq_b = (const float*)d_in[5];
  const float* wk_w = (const float*)d_in[6];
  const float* wk_b = (const float*)d_in[7];
  const float* wv_w = (const float*)d_in[8];
  const float* wv_b = (const float*)d_in[9];
  const float* wo_w = (const float*)d_in[10];
  const float* wo_b = (const float*)d_in[11];

  float* out = (float*)d_out;
  float* attn = (float*)d_out + OUT_ELEMS;

  float* qh = (float*)d_ws;            // [B,H,S,64]
  float* kh = qh + HS_ELEMS;           // [B,H,S,64]
  float* vt = kh + HS_ELEMS;           // [B,H,64,S] (transposed V)
  float* ctx = vt + HS_ELEMS;          // [B,S,768] concat layout
  float* mstat = ctx + OUT_ELEMS;      // [2][B*H*S] rowmax, 1/rowsum

  const dim3 gproj(M_ / 128, D_ / 128);
  xwt_mfma<1><<<gproj, 256, 0, stream>>>(q, wq_w, wq_b, qh);
  xwt_mfma<1><<<gproj, 256, 0, stream>>>(k, wk_w, wk_b, kh);
  xwt_mfma<2><<<gproj, 256, 0, stream>>>(v, wv_w, wv_b, vt);

  const dim3 gstrip(S_ / 128, B_ * H_);
  scores_strip<<<gstrip, 256, 0, stream>>>(qh, kh, mask, attn, mstat);

  pv_fused<<<gstrip, 256, 0, stream>>>(attn, vt, mstat, ctx);

  xwt_mfma<0><<<gproj, 256, 0, stream>>>(ctx, wo_w, wo_b, out);
}